// Round 2
// baseline (354.847 us; speedup 1.0000x reference)
//
#include <hip/hip_runtime.h>

#define HNEG (-1000000000.0f)

constexpr int Nc = 128;
constexpr int Mc = 128;
constexpr int DIAGS = Nc + Mc - 1;  // 255

__device__ __forceinline__ float lse3(float a, float b, float c) {
  float mx = fmaxf(fmaxf(a, b), c);
  return mx + __logf(__expf(a - mx) + __expf(b - mx) + __expf(c - mx));
}

// Forward lattice. One block per batch b; thread j owns column j. Anti-diagonal
// wavefront: at diag d, thread j computes cell (i = d - j, j), states s=0..2:
//   alpha[i,j,0] = th0 + LSE_k(alpha[i-1,j-1,k] + A[k,0])   (neighbor j-1, diag d-2)
//   alpha[i,j,1] = th1 + LSE_k(alpha[i-1,j  ,k] + A[k,1])   (own cell,     diag d-1)
//   alpha[i,j,2] = th2 + LSE_k(alpha[i,  j-1,k] + A[k,2])   (neighbor j-1, diag d-1)
// alpha[0,0,0] = theta[0,0,0] (lse_m := 0 at origin). Out-of-grid cells = NEG.
// LDS ring: 3 diag slots x (128+1 pad) columns x 3 states; pad col 0 stays NEG.
__global__ __launch_bounds__(128) void fwd_kernel(const float* __restrict__ theta,
                                                  const float* __restrict__ A,
                                                  float* __restrict__ out) {
  const int b = blockIdx.x;
  const int j = threadIdx.x;
  const float* th = theta + (size_t)b * (Nc * Mc * 3);
  float* ob = out + (size_t)b * (Nc * Mc * 3);

  __shared__ float sA[9];
  __shared__ float ring[3][Mc + 1][3];
  if (j < 9) sA[j] = A[b * 9 + j];
  {
    float* rf = &ring[0][0][0];
    for (int t = j; t < 3 * (Mc + 1) * 3; t += Mc) rf[t] = HNEG;
  }
  __syncthreads();
  const float A00 = sA[0], A01 = sA[1], A02 = sA[2];
  const float A10 = sA[3], A11 = sA[4], A12 = sA[5];
  const float A20 = sA[6], A21 = sA[7], A22 = sA[8];

  // own cell at previous diag (= (i-1, j)); NEG before first active diag
  float p0 = HNEG, p1 = HNEG, p2 = HNEG;

  // theta prefetch queue (depth 2): cur holds row i = d - j, nxt holds i+1
  float tc0 = 0.f, tc1 = 0.f, tc2 = 0.f, tn0 = 0.f, tn1 = 0.f, tn2 = 0.f;
  if (j == 0) { tc0 = th[0]; tc1 = th[1]; tc2 = th[2]; }
  if (j <= 1) {
    const int i1 = 1 - j;
    const float* p = th + (i1 * Mc + j) * 3;
    tn0 = p[0]; tn1 = p[1]; tn2 = p[2];
  }

  int s0 = 0, s1 = 2, s2 = 1;  // write slot (d), d-1 slot, d-2 slot
  for (int d = 0; d < DIAGS; ++d) {
    const int i = d - j;
    // prefetch theta row i+2 (consumed at iter d+2)
    float tf0 = 0.f, tf1 = 0.f, tf2 = 0.f;
    const int ip = i + 2;
    if (ip >= 0 && ip < Nc) {
      const float* p = th + (ip * Mc + j) * 3;
      tf0 = p[0]; tf1 = p[1]; tf2 = p[2];
    }
    float c0 = HNEG, c1 = HNEG, c2 = HNEG;
    if (i >= 0 && i < Nc) {
      const float* nd1 = ring[s1][j];  // neighbor (j-1) at diag d-1 (pad at col 0)
      const float* nd2 = ring[s2][j];  // neighbor (j-1) at diag d-2
      float lm = lse3(nd2[0] + A00, nd2[1] + A10, nd2[2] + A20);
      if (i == 0 && j == 0) lm = 0.0f;
      float lx = lse3(p0 + A01, p1 + A11, p2 + A21);
      float ly = lse3(nd1[0] + A02, nd1[1] + A12, nd1[2] + A22);
      c0 = tc0 + lm;
      c1 = tc1 + lx;
      c2 = tc2 + ly;
      float* o = ob + (i * Mc + j) * 3;
      o[0] = c0; o[1] = c1; o[2] = c2;
    }
    float* w = ring[s0][j + 1];
    w[0] = c0; w[1] = c1; w[2] = c2;
    __syncthreads();
    p0 = c0; p1 = c1; p2 = c2;
    tc0 = tn0; tc1 = tn1; tc2 = tn2;
    tn0 = tf0; tn1 = tf1; tn2 = tf2;
    const int t = s2; s2 = s1; s1 = s0; s0 = t;  // rotate ring slots
  }
}

// Backward on the flipped grid (p = N-1-i, q = M-1-j), carrying u = g + theta_f:
//   v = [u(p-1,q-1,0), u(p-1,q,1), u(p,q-1,2)]  (shared by all 3 output states)
//   g[.,s] = LSE_k(A[s,k] + v_k);  g = 0 at (p,q) = (0,0);  u = g + theta[i,jj,:]
// beta == g. Thread q owns orig column jj = M-1-q; reads alpha from d_out
// (same-thread, read-before-write) and overwrites with alpha + g - logZ.
__global__ __launch_bounds__(128) void bwd_kernel(const float* __restrict__ theta,
                                                  const float* __restrict__ A,
                                                  float* __restrict__ ob_) {
  const int b = blockIdx.x;
  const int q = threadIdx.x;
  const float* th = theta + (size_t)b * (Nc * Mc * 3);
  float* ob = ob_ + (size_t)b * (Nc * Mc * 3);

  __shared__ float sA[9];
  __shared__ float ring[3][Mc + 1][3];
  __shared__ float sZ;
  if (q < 9) sA[q] = A[b * 9 + q];
  {
    float* rf = &ring[0][0][0];
    for (int t = q; t < 3 * (Mc + 1) * 3; t += Mc) rf[t] = HNEG;
  }
  if (q == 0) {
    sZ = lse3(ob[(Nc * Mc - 1) * 3 + 0], ob[(Nc * Mc - 1) * 3 + 1],
              ob[(Nc * Mc - 1) * 3 + 2]);
  }
  __syncthreads();
  const float A00 = sA[0], A01 = sA[1], A02 = sA[2];
  const float A10 = sA[3], A11 = sA[4], A12 = sA[5];
  const float A20 = sA[6], A21 = sA[7], A22 = sA[8];
  const float logZ = sZ;

  const int jj = Mc - 1 - q;  // orig column owned by this thread
  // own u at previous diag, state 1 (= u(p-1, q, 1))
  float pu1 = HNEG;

  // prefetch queues for theta and alpha at (i, jj); at diag d, i = Nc-1-(d-q).
  float tc0 = 0.f, tc1 = 0.f, tc2 = 0.f, tn0 = 0.f, tn1 = 0.f, tn2 = 0.f;
  float ac0 = 0.f, ac1 = 0.f, ac2 = 0.f, an0 = 0.f, an1 = 0.f, an2 = 0.f;
  if (q == 0) {
    const float* p = th + ((Nc - 1) * Mc + jj) * 3;
    tc0 = p[0]; tc1 = p[1]; tc2 = p[2];
    const float* a = ob + ((Nc - 1) * Mc + jj) * 3;
    ac0 = a[0]; ac1 = a[1]; ac2 = a[2];
  }
  if (q <= 1) {
    const int i1 = Nc - 2 + q;  // row for diag d=1 (valid: q=0 -> N-2, q=1 -> N-1)
    const float* p = th + (i1 * Mc + jj) * 3;
    tn0 = p[0]; tn1 = p[1]; tn2 = p[2];
    const float* a = ob + (i1 * Mc + jj) * 3;
    an0 = a[0]; an1 = a[1]; an2 = a[2];
  }

  int s0 = 0, s1 = 2, s2 = 1;
  for (int d = 0; d < DIAGS; ++d) {
    const int p = d - q;
    const int i = Nc - 1 - p;
    // prefetch row i-2 (consumed at iter d+2)
    float tf0 = 0.f, tf1 = 0.f, tf2 = 0.f, af0 = 0.f, af1 = 0.f, af2 = 0.f;
    const int ipf = i - 2;
    if (ipf >= 0 && ipf < Nc) {
      const float* pp = th + (ipf * Mc + jj) * 3;
      tf0 = pp[0]; tf1 = pp[1]; tf2 = pp[2];
      const float* aa = ob + (ipf * Mc + jj) * 3;
      af0 = aa[0]; af1 = aa[1]; af2 = aa[2];
    }
    float u0 = HNEG, u1 = HNEG, u2 = HNEG;
    if (p >= 0 && p < Nc) {
      const float* nd1 = ring[s1][q];  // neighbor (q-1) at diag d-1
      const float* nd2 = ring[s2][q];  // neighbor (q-1) at diag d-2
      const float v0 = nd2[0];  // u(p-1, q-1, 0)
      const float v1 = pu1;     // u(p-1, q,   1)
      const float v2 = nd1[2];  // u(p,   q-1, 2)
      float g0 = lse3(A00 + v0, A01 + v1, A02 + v2);
      float g1 = lse3(A10 + v0, A11 + v1, A12 + v2);
      float g2 = lse3(A20 + v0, A21 + v1, A22 + v2);
      if (p == 0 && q == 0) { g0 = 0.0f; g1 = 0.0f; g2 = 0.0f; }
      u0 = g0 + tc0;
      u1 = g1 + tc1;
      u2 = g2 + tc2;
      float* o = ob + (i * Mc + jj) * 3;
      o[0] = ac0 + g0 - logZ;
      o[1] = ac1 + g1 - logZ;
      o[2] = ac2 + g2 - logZ;
    }
    float* w = ring[s0][q + 1];
    w[0] = u0; w[1] = u1; w[2] = u2;
    __syncthreads();
    pu1 = u1;
    tc0 = tn0; tc1 = tn1; tc2 = tn2;
    tn0 = tf0; tn1 = tf1; tn2 = tf2;
    ac0 = an0; ac1 = an1; ac2 = an2;
    an0 = af0; an1 = af1; an2 = af2;
    const int t = s2; s2 = s1; s1 = s0; s0 = t;
  }
}

extern "C" void kernel_launch(void* const* d_in, const int* in_sizes, int n_in,
                              void* d_out, int out_size, void* d_ws, size_t ws_size,
                              hipStream_t stream) {
  const float* theta = (const float*)d_in[0];
  const float* A = (const float*)d_in[1];
  float* out = (float*)d_out;
  const int B = in_sizes[1] / 9;  // A is (B, 3, 3)

  fwd_kernel<<<dim3(B), dim3(128), 0, stream>>>(theta, A, out);
  bwd_kernel<<<dim3(B), dim3(128), 0, stream>>>(theta, A, out);
}